// Round 10
// baseline (386.162 us; speedup 1.0000x reference)
//
#include <hip/hip_runtime.h>
#include <hip/hip_bf16.h>

#define NEG_INF -1e20f

typedef __bf16 bf16x8 __attribute__((ext_vector_type(8)));
typedef float  f32x16 __attribute__((ext_vector_type(16)));

__device__ inline unsigned short f2bf(float x) {            // RNE, no NaN inputs
    unsigned u = __float_as_uint(x);
    unsigned r = u + 0x7fffu + ((u >> 16) & 1u);
    return (unsigned short)(r >> 16);
}
__device__ inline float bf2f(unsigned short h) {
    return __uint_as_float((unsigned)h << 16);
}
__device__ inline unsigned fkey(float f) {
    unsigned u = __float_as_uint(f);
    return (u & 0x80000000u) ? ~u : (u | 0x80000000u);
}

// ---------------------------------------------------------------------------
// K0: split ctx AND W into 3 bf16 planes each, one launch. VERBATIM R9.
// ---------------------------------------------------------------------------
__global__ __launch_bounds__(256) void split3_all(
        const float* __restrict__ ctx, const float* __restrict__ W,
        unsigned short* __restrict__ C1, unsigned short* __restrict__ C2,
        unsigned short* __restrict__ C3, unsigned short* __restrict__ W1,
        unsigned short* __restrict__ W2, unsigned short* __restrict__ W3) {
    const int b = blockIdx.x;
    const int t = threadIdx.x;
    const float* src;
    unsigned short *p1, *p2, *p3;
    int base;
    if (b < 2048) { src = ctx; p1 = C1; p2 = C2; p3 = C3; base = b * 1024; }
    else          { src = W;   p1 = W1; p2 = W2; p3 = W3; base = (b - 2048) * 1024; }
#pragma unroll
    for (int it = 0; it < 4; ++it) {
        int i = base + it * 256 + t;
        float4 v = ((const float4*)src)[i];
        ushort4 a, bb, c;
        float r;
        a.x = f2bf(v.x); r = v.x - bf2f(a.x); bb.x = f2bf(r); c.x = f2bf(r - bf2f(bb.x));
        a.y = f2bf(v.y); r = v.y - bf2f(a.y); bb.y = f2bf(r); c.y = f2bf(r - bf2f(bb.y));
        a.z = f2bf(v.z); r = v.z - bf2f(a.z); bb.z = f2bf(r); c.z = f2bf(r - bf2f(bb.z));
        a.w = f2bf(v.w); r = v.w - bf2f(a.w); bb.w = f2bf(r); c.w = f2bf(r - bf2f(bb.w));
        ((ushort4*)p1)[i] = a;
        ((ushort4*)p2)[i] = bb;
        ((ushort4*)p3)[i] = c;
    }
}

// ---------------------------------------------------------------------------
// K1: ctx_fc = relu(context @ W^T), 6-term bf16 emulation on 32x32x16 MFMA.
// Staging byte-identical to R9 (128x128 tile, BK=32, XOR-swizzled
// global_load_lds). Wave 64x64 = 2x2 frags of 32x32; 2 k-halves; 48 MFMA/iter.
// A/B operand layout: m=lane&31, k=(lane>>5)*8+j.
// C/D: col(B-side)=lane&31, row(A-side)=(reg&3)+8*(reg>>2)+4*(lane>>5).
// ---------------------------------------------------------------------------
__global__ __launch_bounds__(256, 2) void fc_mfma6(
        const unsigned short* __restrict__ A1, const unsigned short* __restrict__ A2,
        const unsigned short* __restrict__ A3, const unsigned short* __restrict__ B1,
        const unsigned short* __restrict__ B2, const unsigned short* __restrict__ B3,
        unsigned short* __restrict__ Fhi, unsigned short* __restrict__ Flo) {
    __shared__ char lds[49152];

    const int t     = threadIdx.x;
    const int mBase = blockIdx.x * 128;   // ctx-row tile
    const int hBase = blockIdx.y * 128;   // W-row (output col) tile
    const int w = t >> 6, lane = t & 63;
    const int hl = lane >> 5, l31 = lane & 31;
    const int wn = (w >> 1) * 64;
    const int wm = (w & 1) * 64;

    f32x16 acc[2][2] = {};

    for (int kt = 0; kt < 512; kt += 32) {
#pragma unroll
        for (int p = 0; p < 3; ++p) {
            const unsigned short* pl = (p == 0) ? A1 : (p == 1) ? A2 : A3;
#pragma unroll
            for (int rr = 0; rr < 2; ++rr) {
                int chunk = rr * 256 + t;
                int row   = chunk >> 2;
                int c     = (chunk & 3) ^ ((row >> 1) & 3);
                const unsigned short* g = pl + ((size_t)(mBase + row) * 512 + kt + c * 8);
                char* l = lds + p * 8192 + chunk * 16;
                __builtin_amdgcn_global_load_lds(
                    (const __attribute__((address_space(1))) void*)g,
                    (__attribute__((address_space(3))) void*)l, 16, 0, 0);
            }
        }
#pragma unroll
        for (int p = 0; p < 3; ++p) {
            const unsigned short* pl = (p == 0) ? B1 : (p == 1) ? B2 : B3;
#pragma unroll
            for (int rr = 0; rr < 2; ++rr) {
                int chunk = rr * 256 + t;
                int row   = chunk >> 2;
                int c     = (chunk & 3) ^ ((row >> 1) & 3);
                const unsigned short* g = pl + ((size_t)(hBase + row) * 512 + kt + c * 8);
                char* l = lds + 24576 + p * 8192 + chunk * 16;
                __builtin_amdgcn_global_load_lds(
                    (const __attribute__((address_space(1))) void*)g,
                    (__attribute__((address_space(3))) void*)l, 16, 0, 0);
            }
        }
        __syncthreads();

        bf16x8 a1[2][2], a2[2][2], a3[2][2], b1[2][2], b2[2][2], b3[2][2];
#pragma unroll
        for (int i = 0; i < 2; ++i)
#pragma unroll
            for (int h = 0; h < 2; ++h) {
                int mA = wn + i * 32 + l31;
                int oA = (mA * 4 + ((h * 2 + hl) ^ ((mA >> 1) & 3))) * 16;
                a1[i][h] = *(const bf16x8*)(lds +     0 + oA);
                a2[i][h] = *(const bf16x8*)(lds +  8192 + oA);
                a3[i][h] = *(const bf16x8*)(lds + 16384 + oA);
                int mB = wm + i * 32 + l31;
                int oB = (mB * 4 + ((h * 2 + hl) ^ ((mB >> 1) & 3))) * 16;
                b1[i][h] = *(const bf16x8*)(lds + 24576 + oB);
                b2[i][h] = *(const bf16x8*)(lds + 32768 + oB);
                b3[i][h] = *(const bf16x8*)(lds + 40960 + oB);
            }
#pragma unroll
        for (int i = 0; i < 2; ++i)
#pragma unroll
            for (int j = 0; j < 2; ++j)
#pragma unroll
                for (int h = 0; h < 2; ++h) {
                    acc[i][j] = __builtin_amdgcn_mfma_f32_32x32x16_bf16(a1[i][h], b1[j][h], acc[i][j], 0, 0, 0);
                    acc[i][j] = __builtin_amdgcn_mfma_f32_32x32x16_bf16(a1[i][h], b2[j][h], acc[i][j], 0, 0, 0);
                    acc[i][j] = __builtin_amdgcn_mfma_f32_32x32x16_bf16(a2[i][h], b1[j][h], acc[i][j], 0, 0, 0);
                    acc[i][j] = __builtin_amdgcn_mfma_f32_32x32x16_bf16(a2[i][h], b2[j][h], acc[i][j], 0, 0, 0);
                    acc[i][j] = __builtin_amdgcn_mfma_f32_32x32x16_bf16(a1[i][h], b3[j][h], acc[i][j], 0, 0, 0);
                    acc[i][j] = __builtin_amdgcn_mfma_f32_32x32x16_bf16(a3[i][h], b1[j][h], acc[i][j], 0, 0, 0);
                }
        __syncthreads();
    }

    // epilogue: relu + hi/lo split, per-wave LDS transpose (32 rows x 68 u32
    // stride), then 128B-per-plane ushort4 line stores. Wave-private region.
    unsigned* tb = (unsigned*)(lds + w * 8704);
    const int rg = lane >> 4, c4 = lane & 15;
#pragma unroll
    for (int i = 0; i < 2; ++i) {
#pragma unroll
        for (int j = 0; j < 2; ++j)
#pragma unroll
            for (int reg = 0; reg < 16; ++reg) {
                int rowl = (reg & 3) + 8 * (reg >> 2) + 4 * hl;
                float v = fmaxf(acc[i][j][reg], 0.f);
                unsigned short hi_ = f2bf(v);
                unsigned short lo_ = f2bf(v - bf2f(hi_));
                tb[rowl * 68 + j * 32 + l31] = (unsigned)hi_ | ((unsigned)lo_ << 16);
            }
        // wave-lockstep: all writes above precede reads below within the wave
#pragma unroll
        for (int pass = 0; pass < 8; ++pass) {
            int row = pass * 4 + rg;
            uint4 pk = *(const uint4*)&tb[row * 68 + c4 * 4];
            ushort4 h, l;
            h.x = (unsigned short)pk.x; l.x = (unsigned short)(pk.x >> 16);
            h.y = (unsigned short)pk.y; l.y = (unsigned short)(pk.y >> 16);
            h.z = (unsigned short)pk.z; l.z = (unsigned short)(pk.z >> 16);
            h.w = (unsigned short)pk.w; l.w = (unsigned short)(pk.w >> 16);
            size_t off = (size_t)(mBase + wn + i * 32 + row) * 512 + hBase + wm + c4 * 4;
            *(ushort4*)(Fhi + off) = h;
            *(ushort4*)(Flo + off) = l;
        }
    }
}

// ---------------------------------------------------------------------------
// K2: att = F F^T via bf16x3 emulation on 32x32x16 MFMA. Staging byte-
// identical to R2/R9. Epilogue: direct scalar stores — each inst writes two
// full 128B line segments (32 lanes x 4B contiguous per half-wave).
// ---------------------------------------------------------------------------
__global__ __launch_bounds__(256, 2) void att_mfma(
        const unsigned short* __restrict__ Fhi, const unsigned short* __restrict__ Flo,
        const int* __restrict__ mask, float* __restrict__ out) {
    __shared__ char lds[32768];

    const int t     = threadIdx.x;
    const int b     = blockIdx.z;
    const int mBase = blockIdx.x * 128;
    const int nBase = blockIdx.y * 128;
    const int w  = t >> 6, lane = t & 63;
    const int hl = lane >> 5, l31 = lane & 31;
    const int wn = (w >> 1) * 64;
    const int wm = (w & 1) * 64;
    const size_t rowB = (size_t)b * 2048;

    f32x16 acc[2][2] = {};

    for (int kt = 0; kt < 512; kt += 32) {
#pragma unroll
        for (int p = 0; p < 4; ++p) {
            const unsigned short* plane = (p & 1) ? Flo : Fhi;
            int rbase = (p < 2) ? nBase : mBase;
#pragma unroll
            for (int r = 0; r < 2; ++r) {
                int chunk = r * 256 + t;
                int row   = chunk >> 2;
                int c     = (chunk & 3) ^ ((row >> 1) & 3);
                const unsigned short* g =
                    plane + ((rowB + rbase + row) * 512 + kt + c * 8);
                char* l = lds + p * 8192 + chunk * 16;
                __builtin_amdgcn_global_load_lds(
                    (const __attribute__((address_space(1))) void*)g,
                    (__attribute__((address_space(3))) void*)l, 16, 0, 0);
            }
        }
        __syncthreads();

        bf16x8 ah[2][2], al[2][2], bh[2][2], bl[2][2];
#pragma unroll
        for (int i = 0; i < 2; ++i)
#pragma unroll
            for (int h = 0; h < 2; ++h) {
                int mA = wn + i * 32 + l31;
                int oA = (mA * 4 + ((h * 2 + hl) ^ ((mA >> 1) & 3))) * 16;
                ah[i][h] = *(const bf16x8*)(lds +     0 + oA);
                al[i][h] = *(const bf16x8*)(lds +  8192 + oA);
                int mB = wm + i * 32 + l31;
                int oB = (mB * 4 + ((h * 2 + hl) ^ ((mB >> 1) & 3))) * 16;
                bh[i][h] = *(const bf16x8*)(lds + 16384 + oB);
                bl[i][h] = *(const bf16x8*)(lds + 24576 + oB);
            }
#pragma unroll
        for (int i = 0; i < 2; ++i)
#pragma unroll
            for (int j = 0; j < 2; ++j)
#pragma unroll
                for (int h = 0; h < 2; ++h) {
                    acc[i][j] = __builtin_amdgcn_mfma_f32_32x32x16_bf16(ah[i][h], bh[j][h], acc[i][j], 0, 0, 0);
                    acc[i][j] = __builtin_amdgcn_mfma_f32_32x32x16_bf16(ah[i][h], bl[j][h], acc[i][j], 0, 0, 0);
                    acc[i][j] = __builtin_amdgcn_mfma_f32_32x32x16_bf16(al[i][h], bh[j][h], acc[i][j], 0, 0, 0);
                }
        __syncthreads();
    }

    // epilogue: mask + direct stores (full 128B segments per half-wave)
    const int* mb = mask + b * 2048;
    float* outB = out + (size_t)b * 2048 * 2048;
    int cm[2];
#pragma unroll
    for (int j = 0; j < 2; ++j) cm[j] = mb[mBase + wm + j * 32 + l31];

#pragma unroll
    for (int i = 0; i < 2; ++i) {
        int rm[16];
#pragma unroll
        for (int reg = 0; reg < 16; ++reg) {
            int rowl = (reg & 3) + 8 * (reg >> 2) + 4 * hl;
            rm[reg] = mb[nBase + wn + i * 32 + rowl];
        }
#pragma unroll
        for (int j = 0; j < 2; ++j) {
            float* basep = outB + (size_t)(nBase + wn + i * 32) * 2048
                                + mBase + wm + j * 32 + l31;
#pragma unroll
            for (int reg = 0; reg < 16; ++reg) {
                int rowl = (reg & 3) + 8 * (reg >> 2) + 4 * hl;
                float v = ((rm[reg] != 0) & (cm[j] != 0)) ? acc[i][j][reg] : NEG_INF;
                basep[(size_t)rowl * 2048] = v;
            }
        }
    }
}

// ---------------------------------------------------------------------------
// K3: per-row top-10 -> keep winners, fill -1e20. VERBATIM topk v2 (R6).
// ---------------------------------------------------------------------------
__global__ __launch_bounds__(256) void topk_rows(float* __restrict__ att) {
    __shared__ float patch[2048];
    __shared__ unsigned long long cand[40];
    __shared__ int   top_i[10];
    __shared__ float top_v[10];

    const int t    = threadIdx.x;
    const int lane = t & 63;
    const int w    = t >> 6;
    float* row = att + (size_t)blockIdx.x * 2048;

    float4 a = ((const float4*)row)[2 * t];
    float4 c = ((const float4*)row)[2 * t + 1];
    float v[8] = {a.x, a.y, a.z, a.w, c.x, c.y, c.z, c.w};

    unsigned key[8];
#pragma unroll
    for (int j = 0; j < 8; ++j) key[j] = fkey(v[j]);

    unsigned lk = key[0]; int lj = 0;
#pragma unroll
    for (int j = 1; j < 8; ++j)
        if (key[j] > lk) { lk = key[j]; lj = j; }

    for (int r = 0; r < 10; ++r) {
        unsigned M = lk;
#pragma unroll
        for (int off = 1; off < 64; off <<= 1) {
            unsigned o = __shfl_xor(M, off, 64);
            M = (o > M) ? o : M;
        }
        unsigned long long ball = __ballot(lk == M);
        int src  = __ffsll(ball) - 1;
        int widx = __shfl(t * 8 + lj, src, 64);
        if (lane == 0)
            cand[w * 10 + r] =
                ((unsigned long long)M << 32) | (unsigned)(~(unsigned)widx);
        if (lane == src) {
            key[lj] = 0u;
            lk = key[0]; lj = 0;
#pragma unroll
            for (int j = 1; j < 8; ++j)
                if (key[j] > lk) { lk = key[j]; lj = j; }
        }
    }
    __syncthreads();

    if (w == 0) {
        unsigned long long k2 = (lane < 40) ? cand[lane] : 0ull;
        for (int r = 0; r < 10; ++r) {
            unsigned long long m = k2;
#pragma unroll
            for (int off = 1; off < 64; off <<= 1) {
                unsigned long long o = __shfl_xor(m, off, 64);
                m = (o > m) ? o : m;
            }
            if (lane == r) {
                unsigned hu = (unsigned)(m >> 32);
                unsigned fu = (hu & 0x80000000u) ? (hu ^ 0x80000000u) : ~hu;
                top_v[r] = __uint_as_float(fu);
                top_i[r] = (int)(~(unsigned)(m & 0xffffffffu));
            }
            if (k2 == m) k2 = 0ull;
        }
    }

    float4 ninf4 = make_float4(NEG_INF, NEG_INF, NEG_INF, NEG_INF);
    ((float4*)patch)[2 * t]     = ninf4;
    ((float4*)patch)[2 * t + 1] = ninf4;
    __syncthreads();
    if (t < 10) patch[top_i[t]] = top_v[t];
    __syncthreads();
    ((float4*)row)[2 * t]     = ((float4*)patch)[2 * t];
    ((float4*)row)[2 * t + 1] = ((float4*)patch)[2 * t + 1];
}

// ---------------------------------------------------------------------------
extern "C" void kernel_launch(void* const* d_in, const int* in_sizes, int n_in,
                              void* d_out, int out_size, void* d_ws, size_t ws_size,
                              hipStream_t stream) {
    const float* ctx  = (const float*)d_in[0];   // [8, 2048, 512]
    const float* W    = (const float*)d_in[1];   // [512, 512]
    const int*   mask = (const int*)d_in[2];     // [8, 2048]
    float* out = (float*)d_out;                  // [8, 2048, 2048]

    // bf16 triple-planes for ctx and W live in d_out (dead until att_mfma)
    const size_t CN = (size_t)16384 * 512;       // 8,388,608
    const size_t WN = (size_t)512 * 512;
    unsigned short* C1 = (unsigned short*)d_out;
    unsigned short* C2 = C1 + CN;
    unsigned short* C3 = C2 + CN;
    unsigned short* W1 = C3 + CN;
    unsigned short* W2 = W1 + WN;
    unsigned short* W3 = W2 + WN;                // ends at 51.9 MB < 134 MB

    unsigned short* Fhi = (unsigned short*)d_ws; // [16384, 512] bf16
    unsigned short* Flo = Fhi + CN;

    dim3 blk(256);
    split3_all<<<dim3(2112), blk, 0, stream>>>(ctx, W, C1, C2, C3, W1, W2, W3);
    fc_mfma6<<<dim3(128, 4), blk, 0, stream>>>(C1, C2, C3, W1, W2, W3, Fhi, Flo);
    att_mfma<<<dim3(16, 16, 8), blk, 0, stream>>>(Fhi, Flo, mask, out);
    topk_rows<<<dim3(16384), blk, 0, stream>>>(out);
}

// Round 11
// 366.499 us; speedup vs baseline: 1.0537x; 1.0537x over previous
//
#include <hip/hip_runtime.h>
#include <hip/hip_bf16.h>

#define NEG_INF -1e20f

typedef __bf16 bf16x8 __attribute__((ext_vector_type(8)));
typedef float  f32x4  __attribute__((ext_vector_type(4)));

__device__ inline unsigned short f2bf(float x) {            // RNE, no NaN inputs
    unsigned u = __float_as_uint(x);
    unsigned r = u + 0x7fffu + ((u >> 16) & 1u);
    return (unsigned short)(r >> 16);
}
__device__ inline float bf2f(unsigned short h) {
    return __uint_as_float((unsigned)h << 16);
}
__device__ inline unsigned fkey(float f) {
    unsigned u = __float_as_uint(f);
    return (u & 0x80000000u) ? ~u : (u | 0x80000000u);
}

// ---------------------------------------------------------------------------
// K0: split ctx AND W into 3 bf16 planes each, one launch. VERBATIM R9.
// ---------------------------------------------------------------------------
__global__ __launch_bounds__(256) void split3_all(
        const float* __restrict__ ctx, const float* __restrict__ W,
        unsigned short* __restrict__ C1, unsigned short* __restrict__ C2,
        unsigned short* __restrict__ C3, unsigned short* __restrict__ W1,
        unsigned short* __restrict__ W2, unsigned short* __restrict__ W3) {
    const int b = blockIdx.x;
    const int t = threadIdx.x;
    const float* src;
    unsigned short *p1, *p2, *p3;
    int base;
    if (b < 2048) { src = ctx; p1 = C1; p2 = C2; p3 = C3; base = b * 1024; }
    else          { src = W;   p1 = W1; p2 = W2; p3 = W3; base = (b - 2048) * 1024; }
#pragma unroll
    for (int it = 0; it < 4; ++it) {
        int i = base + it * 256 + t;
        float4 v = ((const float4*)src)[i];
        ushort4 a, bb, c;
        float r;
        a.x = f2bf(v.x); r = v.x - bf2f(a.x); bb.x = f2bf(r); c.x = f2bf(r - bf2f(bb.x));
        a.y = f2bf(v.y); r = v.y - bf2f(a.y); bb.y = f2bf(r); c.y = f2bf(r - bf2f(bb.y));
        a.z = f2bf(v.z); r = v.z - bf2f(a.z); bb.z = f2bf(r); c.z = f2bf(r - bf2f(bb.z));
        a.w = f2bf(v.w); r = v.w - bf2f(a.w); bb.w = f2bf(r); c.w = f2bf(r - bf2f(bb.w));
        ((ushort4*)p1)[i] = a;
        ((ushort4*)p2)[i] = bb;
        ((ushort4*)p3)[i] = c;
    }
}

// ---------------------------------------------------------------------------
// K1: ctx_fc = relu(context @ W^T) via 6-term bf16 MFMA, 128x128 tile,
// 16x16x32 shape. VERBATIM R9 (best round: 374.6 us).
// ---------------------------------------------------------------------------
__global__ __launch_bounds__(256, 2) void fc_mfma6(
        const unsigned short* __restrict__ A1, const unsigned short* __restrict__ A2,
        const unsigned short* __restrict__ A3, const unsigned short* __restrict__ B1,
        const unsigned short* __restrict__ B2, const unsigned short* __restrict__ B3,
        unsigned short* __restrict__ Fhi, unsigned short* __restrict__ Flo) {
    __shared__ char lds[49152];

    const int t     = threadIdx.x;
    const int mBase = blockIdx.x * 128;   // ctx-row tile
    const int hBase = blockIdx.y * 128;   // W-row (output col) tile
    const int w = t >> 6, lane = t & 63;
    const int q = lane >> 4, ln = lane & 15;
    const int wn = (w >> 1) * 64;
    const int wm = (w & 1) * 64;

    f32x4 acc[4][4] = {};

    for (int kt = 0; kt < 512; kt += 32) {
#pragma unroll
        for (int p = 0; p < 3; ++p) {
            const unsigned short* pl = (p == 0) ? A1 : (p == 1) ? A2 : A3;
#pragma unroll
            for (int rr = 0; rr < 2; ++rr) {
                int chunk = rr * 256 + t;
                int row   = chunk >> 2;
                int c     = (chunk & 3) ^ ((row >> 1) & 3);
                const unsigned short* g = pl + ((size_t)(mBase + row) * 512 + kt + c * 8);
                char* l = lds + p * 8192 + chunk * 16;
                __builtin_amdgcn_global_load_lds(
                    (const __attribute__((address_space(1))) void*)g,
                    (__attribute__((address_space(3))) void*)l, 16, 0, 0);
            }
        }
#pragma unroll
        for (int p = 0; p < 3; ++p) {
            const unsigned short* pl = (p == 0) ? B1 : (p == 1) ? B2 : B3;
#pragma unroll
            for (int rr = 0; rr < 2; ++rr) {
                int chunk = rr * 256 + t;
                int row   = chunk >> 2;
                int c     = (chunk & 3) ^ ((row >> 1) & 3);
                const unsigned short* g = pl + ((size_t)(hBase + row) * 512 + kt + c * 8);
                char* l = lds + 24576 + p * 8192 + chunk * 16;
                __builtin_amdgcn_global_load_lds(
                    (const __attribute__((address_space(1))) void*)g,
                    (__attribute__((address_space(3))) void*)l, 16, 0, 0);
            }
        }
        __syncthreads();

        bf16x8 a1[4], a2[4], a3[4], b1[4], b2[4], b3[4];
#pragma unroll
        for (int i = 0; i < 4; ++i) {
            int mA = wn + i * 16 + ln;
            int oA = (mA * 4 + (q ^ ((mA >> 1) & 3))) * 16;
            a1[i] = *(const bf16x8*)(lds +     0 + oA);
            a2[i] = *(const bf16x8*)(lds +  8192 + oA);
            a3[i] = *(const bf16x8*)(lds + 16384 + oA);
            int mB = wm + i * 16 + ln;
            int oB = (mB * 4 + (q ^ ((mB >> 1) & 3))) * 16;
            b1[i] = *(const bf16x8*)(lds + 24576 + oB);
            b2[i] = *(const bf16x8*)(lds + 32768 + oB);
            b3[i] = *(const bf16x8*)(lds + 40960 + oB);
        }
#pragma unroll
        for (int i = 0; i < 4; ++i)
#pragma unroll
            for (int j = 0; j < 4; ++j) {
                acc[i][j] = __builtin_amdgcn_mfma_f32_16x16x32_bf16(a1[i], b1[j], acc[i][j], 0, 0, 0);
                acc[i][j] = __builtin_amdgcn_mfma_f32_16x16x32_bf16(a1[i], b2[j], acc[i][j], 0, 0, 0);
                acc[i][j] = __builtin_amdgcn_mfma_f32_16x16x32_bf16(a2[i], b1[j], acc[i][j], 0, 0, 0);
                acc[i][j] = __builtin_amdgcn_mfma_f32_16x16x32_bf16(a2[i], b2[j], acc[i][j], 0, 0, 0);
                acc[i][j] = __builtin_amdgcn_mfma_f32_16x16x32_bf16(a1[i], b3[j], acc[i][j], 0, 0, 0);
                acc[i][j] = __builtin_amdgcn_mfma_f32_16x16x32_bf16(a3[i], b1[j], acc[i][j], 0, 0, 0);
            }
        __syncthreads();
    }

    // epilogue: per-wave LDS transpose (stride 68 u32), full-line stores.
    unsigned* tb = (unsigned*)(lds + w * 4352);
    const int rg = lane >> 4;
    const int c4 = lane & 15;
#pragma unroll
    for (int i = 0; i < 4; ++i) {
#pragma unroll
        for (int j = 0; j < 4; ++j)
#pragma unroll
            for (int r = 0; r < 4; ++r) {
                float v = fmaxf(acc[i][j][r], 0.f);
                unsigned short hi = f2bf(v);
                unsigned short lo = f2bf(v - bf2f(hi));
                tb[(q * 4 + r) * 68 + j * 16 + ln] =
                    (unsigned)hi | ((unsigned)lo << 16);
            }
#pragma unroll
        for (int it = 0; it < 4; ++it) {
            int row = it * 4 + rg;
            uint4 pk = *(const uint4*)&tb[row * 68 + c4 * 4];
            ushort4 h, l;
            h.x = (unsigned short)pk.x; l.x = (unsigned short)(pk.x >> 16);
            h.y = (unsigned short)pk.y; l.y = (unsigned short)(pk.y >> 16);
            h.z = (unsigned short)pk.z; l.z = (unsigned short)(pk.z >> 16);
            h.w = (unsigned short)pk.w; l.w = (unsigned short)(pk.w >> 16);
            size_t off = (size_t)(mBase + wn + i * 16 + row) * 512 + hBase + wm + c4 * 4;
            *(ushort4*)(Fhi + off) = h;
            *(ushort4*)(Flo + off) = l;
        }
    }
}

// ---------------------------------------------------------------------------
// K2: att = F F^T via bf16x3 MFMA — SYMMETRIC: only the 136 upper-triangle
// tile-pairs (ti<=tj) are computed; i!=j tiles are written twice (straight +
// mirrored transpose). Values bit-identical to computing both directions
// (same dot products, same k-order). K-loop/staging verbatim R9.
// ---------------------------------------------------------------------------
__global__ __launch_bounds__(256, 2) void att_mfma_sym(
        const unsigned short* __restrict__ Fhi, const unsigned short* __restrict__ Flo,
        const int* __restrict__ mask, float* __restrict__ out) {
    __shared__ char lds[32768];

    const int t = threadIdx.x;
    const int b = blockIdx.z;
    // decode pair index -> (ti <= tj)
    int p = blockIdx.x, ti = 0;
    while (p >= 16 - ti) { p -= 16 - ti; ++ti; }
    const int tj = ti + p;
    const int nBase = ti * 128;          // A-side rows
    const int mBase = tj * 128;          // B-side rows
    const int w    = t >> 6, lane = t & 63;
    const int q    = lane >> 4, ln = lane & 15;
    const int wn   = (w >> 1) * 64;
    const int wm   = (w & 1) * 64;
    const size_t rowB = (size_t)b * 2048;

    f32x4 acc[4][4] = {};

    for (int kt = 0; kt < 512; kt += 32) {
#pragma unroll
        for (int pp = 0; pp < 4; ++pp) {
            const unsigned short* plane = (pp & 1) ? Flo : Fhi;
            int rbase = (pp < 2) ? nBase : mBase;
#pragma unroll
            for (int r = 0; r < 2; ++r) {
                int chunk = r * 256 + t;
                int row   = chunk >> 2;
                int c     = (chunk & 3) ^ ((row >> 1) & 3);
                const unsigned short* g =
                    plane + ((rowB + rbase + row) * 512 + kt + c * 8);
                char* l = lds + pp * 8192 + chunk * 16;
                __builtin_amdgcn_global_load_lds(
                    (const __attribute__((address_space(1))) void*)g,
                    (__attribute__((address_space(3))) void*)l, 16, 0, 0);
            }
        }
        __syncthreads();

        bf16x8 ah[4], al[4], bh[4], bl[4];
#pragma unroll
        for (int i = 0; i < 4; ++i) {
            int mA = wn + i * 16 + ln;
            int oA = (mA * 4 + (q ^ ((mA >> 1) & 3))) * 16;
            ah[i] = *(const bf16x8*)(lds +     0 + oA);
            al[i] = *(const bf16x8*)(lds +  8192 + oA);
            int mB = wm + i * 16 + ln;
            int oB = (mB * 4 + (q ^ ((mB >> 1) & 3))) * 16;
            bh[i] = *(const bf16x8*)(lds + 16384 + oB);
            bl[i] = *(const bf16x8*)(lds + 24576 + oB);
        }
#pragma unroll
        for (int i = 0; i < 4; ++i)
#pragma unroll
            for (int j = 0; j < 4; ++j) {
                acc[i][j] = __builtin_amdgcn_mfma_f32_16x16x32_bf16(ah[i], bh[j], acc[i][j], 0, 0, 0);
                acc[i][j] = __builtin_amdgcn_mfma_f32_16x16x32_bf16(ah[i], bl[j], acc[i][j], 0, 0, 0);
                acc[i][j] = __builtin_amdgcn_mfma_f32_16x16x32_bf16(al[i], bh[j], acc[i][j], 0, 0, 0);
            }
        __syncthreads();
    }

    // epilogue: mask -> per-wave LDS transpose (stride 68 f32); straight
    // float4 row stores + (ti!=tj) mirrored float4 stores from column reads.
    const int* mb = mask + b * 2048;
    float* outB = out + (size_t)b * 2048 * 2048;
    int cm[4];
#pragma unroll
    for (int j = 0; j < 4; ++j) cm[j] = mb[mBase + wm + j * 16 + ln];

    float* tb = (float*)(lds + w * 4352);
    const int rg = lane >> 4;
    const int c4 = lane & 15;
    const bool mirror = (ti != tj);
#pragma unroll
    for (int i = 0; i < 4; ++i) {
        int n0 = nBase + wn + i * 16;
        int rmv[4];
#pragma unroll
        for (int r = 0; r < 4; ++r) rmv[r] = mb[n0 + q * 4 + r];
#pragma unroll
        for (int j = 0; j < 4; ++j)
#pragma unroll
            for (int r = 0; r < 4; ++r) {
                float v = ((rmv[r] != 0) & (cm[j] != 0)) ? acc[i][j][r] : NEG_INF;
                tb[(q * 4 + r) * 68 + j * 16 + ln] = v;
            }
        // straight: rows n0..n0+15, 64 m-cols (wave-lockstep orders LDS ops)
#pragma unroll
        for (int it = 0; it < 4; ++it) {
            int row = it * 4 + rg;
            float4 vv = *(const float4*)&tb[row * 68 + c4 * 4];
            *(float4*)(outB + (size_t)(n0 + row) * 2048 + mBase + wm + c4 * 4) = vv;
        }
        // mirror: rows mBase+wm+lane (64), cols n0..n0+15 (column reads,
        // consecutive-lane addrs -> 2 lanes/bank, free)
        if (mirror) {
#pragma unroll
            for (int ps = 0; ps < 4; ++ps) {
                float4 mv;
                mv.x = tb[(ps * 4 + 0) * 68 + lane];
                mv.y = tb[(ps * 4 + 1) * 68 + lane];
                mv.z = tb[(ps * 4 + 2) * 68 + lane];
                mv.w = tb[(ps * 4 + 3) * 68 + lane];
                *(float4*)(outB + (size_t)(mBase + wm + lane) * 2048 + n0 + ps * 4) = mv;
            }
        }
    }
}

// ---------------------------------------------------------------------------
// K3: per-row top-10 -> keep winners, fill -1e20. VERBATIM topk v2 (R6).
// ---------------------------------------------------------------------------
__global__ __launch_bounds__(256) void topk_rows(float* __restrict__ att) {
    __shared__ float patch[2048];
    __shared__ unsigned long long cand[40];
    __shared__ int   top_i[10];
    __shared__ float top_v[10];

    const int t    = threadIdx.x;
    const int lane = t & 63;
    const int w    = t >> 6;
    float* row = att + (size_t)blockIdx.x * 2048;

    float4 a = ((const float4*)row)[2 * t];
    float4 c = ((const float4*)row)[2 * t + 1];
    float v[8] = {a.x, a.y, a.z, a.w, c.x, c.y, c.z, c.w};

    unsigned key[8];
#pragma unroll
    for (int j = 0; j < 8; ++j) key[j] = fkey(v[j]);

    unsigned lk = key[0]; int lj = 0;
#pragma unroll
    for (int j = 1; j < 8; ++j)
        if (key[j] > lk) { lk = key[j]; lj = j; }

    for (int r = 0; r < 10; ++r) {
        unsigned M = lk;
#pragma unroll
        for (int off = 1; off < 64; off <<= 1) {
            unsigned o = __shfl_xor(M, off, 64);
            M = (o > M) ? o : M;
        }
        unsigned long long ball = __ballot(lk == M);
        int src  = __ffsll(ball) - 1;
        int widx = __shfl(t * 8 + lj, src, 64);
        if (lane == 0)
            cand[w * 10 + r] =
                ((unsigned long long)M << 32) | (unsigned)(~(unsigned)widx);
        if (lane == src) {
            key[lj] = 0u;
            lk = key[0]; lj = 0;
#pragma unroll
            for (int j = 1; j < 8; ++j)
                if (key[j] > lk) { lk = key[j]; lj = j; }
        }
    }
    __syncthreads();

    if (w == 0) {
        unsigned long long k2 = (lane < 40) ? cand[lane] : 0ull;
        for (int r = 0; r < 10; ++r) {
            unsigned long long m = k2;
#pragma unroll
            for (int off = 1; off < 64; off <<= 1) {
                unsigned long long o = __shfl_xor(m, off, 64);
                m = (o > m) ? o : m;
            }
            if (lane == r) {
                unsigned hu = (unsigned)(m >> 32);
                unsigned fu = (hu & 0x80000000u) ? (hu ^ 0x80000000u) : ~hu;
                top_v[r] = __uint_as_float(fu);
                top_i[r] = (int)(~(unsigned)(m & 0xffffffffu));
            }
            if (k2 == m) k2 = 0ull;
        }
    }

    float4 ninf4 = make_float4(NEG_INF, NEG_INF, NEG_INF, NEG_INF);
    ((float4*)patch)[2 * t]     = ninf4;
    ((float4*)patch)[2 * t + 1] = ninf4;
    __syncthreads();
    if (t < 10) patch[top_i[t]] = top_v[t];
    __syncthreads();
    ((float4*)row)[2 * t]     = ((float4*)patch)[2 * t];
    ((float4*)row)[2 * t + 1] = ((float4*)patch)[2 * t + 1];
}

// ---------------------------------------------------------------------------
extern "C" void kernel_launch(void* const* d_in, const int* in_sizes, int n_in,
                              void* d_out, int out_size, void* d_ws, size_t ws_size,
                              hipStream_t stream) {
    const float* ctx  = (const float*)d_in[0];   // [8, 2048, 512]
    const float* W    = (const float*)d_in[1];   // [512, 512]
    const int*   mask = (const int*)d_in[2];     // [8, 2048]
    float* out = (float*)d_out;                  // [8, 2048, 2048]

    // bf16 triple-planes for ctx and W live in d_out (dead until att writes)
    const size_t CN = (size_t)16384 * 512;       // 8,388,608
    const size_t WN = (size_t)512 * 512;
    unsigned short* C1 = (unsigned short*)d_out;
    unsigned short* C2 = C1 + CN;
    unsigned short* C3 = C2 + CN;
    unsigned short* W1 = C3 + CN;
    unsigned short* W2 = W1 + WN;
    unsigned short* W3 = W2 + WN;                // ends at 51.9 MB < 134 MB

    unsigned short* Fhi = (unsigned short*)d_ws; // [16384, 512] bf16
    unsigned short* Flo = Fhi + CN;

    dim3 blk(256);
    split3_all<<<dim3(2112), blk, 0, stream>>>(ctx, W, C1, C2, C3, W1, W2, W3);
    fc_mfma6<<<dim3(128, 4), blk, 0, stream>>>(C1, C2, C3, W1, W2, W3, Fhi, Flo);
    att_mfma_sym<<<dim3(136, 1, 8), blk, 0, stream>>>(Fhi, Flo, mask, out);
    topk_rows<<<dim3(16384), blk, 0, stream>>>(out);
}